// Round 8
// baseline (102.956 us; speedup 1.0000x reference)
//
#include <hip/hip_runtime.h>

// B=8, C=256, H=W=128 fixed. n = 2^25 f32/tensor, n4 = 2^23 float4.
// Plane = 2^12 float4 = 64 KiB. Grid 2048 x 256: block b <-> plane b,
// channel c = b & 255 (mask block-uniform).
//
// KEY IDEA (R8): y1 and y2 are independent plane-copies once the mask is
// known. Each block runs TWO SEQUENTIAL 1R:1W copy phases:
//   phase A: y1[plane] = (m&1 ? x0 : x1)[plane]
//   phase B: y2[plane] = (m&2 ? x1 : x0)[plane]
// -> per-wave stream pattern is exactly the 2-stream copy that hits
// 6.29 TB/s (m13), instead of the 4-stream mix measured at ~5.36 TB/s.
// No data branch in the copy loops at all - just a pointer select.
//
// __launch_bounds__(256, 8): pin VGPR <= 64 -> 8 waves/SIMD, all 2048
// blocks co-resident (R5-proven with this contiguous layout, no guards).

typedef float f32x4 __attribute__((ext_vector_type(4)));

#define NCH 256

__global__ __launch_bounds__(256, 8) void fused_kernel(
    const float* __restrict__ w1, const float* __restrict__ w2,
    const f32x4* __restrict__ x0, const f32x4* __restrict__ x1,
    f32x4* __restrict__ y1, f32x4* __restrict__ y2)
{
    __shared__ float redf[16];          // min1[4] max1[4] min2[4] max2[4]
    __shared__ int   hist1[NCH], hist2[NCH];
    __shared__ int   redi[8];           // best1[4] best2[4]
    __shared__ unsigned int code_s[NCH];

    const int t    = threadIdx.x;       // one channel each
    const int lane = t & 63;
    const int wid  = t >> 6;

    // ---- fused mask preamble: both weight vectors, 4 barriers ----
    const float b1 = fabsf(w1[t]);
    const float b2 = fabsf(w2[t]);

    float mn1 = b1, mx1 = b1, mn2 = b2, mx2 = b2;
#pragma unroll
    for (int off = 32; off > 0; off >>= 1) {
        mn1 = fminf(mn1, __shfl_xor(mn1, off));
        mx1 = fmaxf(mx1, __shfl_xor(mx1, off));
        mn2 = fminf(mn2, __shfl_xor(mn2, off));
        mx2 = fmaxf(mx2, __shfl_xor(mx2, off));
    }
    if (lane == 0) {
        redf[wid] = mn1; redf[4 + wid] = mx1;
        redf[8 + wid] = mn2; redf[12 + wid] = mx2;
    }
    hist1[t] = 0; hist2[t] = 0;
    __syncthreads();

    const float wmin1 = fminf(fminf(redf[0], redf[1]), fminf(redf[2], redf[3]));
    const float wmax1 = fmaxf(fmaxf(redf[4], redf[5]), fmaxf(redf[6], redf[7]));
    const float wmin2 = fminf(fminf(redf[8], redf[9]), fminf(redf[10], redf[11]));
    const float wmax2 = fmaxf(fmaxf(redf[12], redf[13]), fmaxf(redf[14], redf[15]));

    // torch.histc semantics, f32 op order identical to reference
    int idx1 = (int)floorf((b1 - wmin1) / (wmax1 - wmin1) * 256.0f);
    idx1 = idx1 < 0 ? 0 : (idx1 > 255 ? 255 : idx1);
    atomicAdd(&hist1[idx1], 1);
    int idx2 = (int)floorf((b2 - wmin2) / (wmax2 - wmin2) * 256.0f);
    idx2 = idx2 < 0 ? 0 : (idx2 > 255 ? 255 : idx2);
    atomicAdd(&hist2[idx2], 1);
    __syncthreads();

    // first i with diff[i] <= 0 < diff[i+1]; fallback 0
    int best1 = 0x7fffffff, best2 = 0x7fffffff;
    if (t < 254) {
        int d0 = hist1[t + 1] - hist1[t];
        int d1 = hist1[t + 2] - hist1[t + 1];
        if (d0 <= 0 && d1 > 0) best1 = t;
        d0 = hist2[t + 1] - hist2[t];
        d1 = hist2[t + 2] - hist2[t + 1];
        if (d0 <= 0 && d1 > 0) best2 = t;
    }
#pragma unroll
    for (int off = 32; off > 0; off >>= 1) {
        best1 = min(best1, __shfl_xor(best1, off));
        best2 = min(best2, __shfl_xor(best2, off));
    }
    if (lane == 0) { redi[wid] = best1; redi[4 + wid] = best2; }
    __syncthreads();

    int i1 = min(min(redi[0], redi[1]), min(redi[2], redi[3]));
    int i2 = min(min(redi[4], redi[5]), min(redi[6], redi[7]));
    i1 = (i1 == 0x7fffffff) ? 0 : i1;
    i2 = (i2 == 0x7fffffff) ? 0 : i2;

    const float thr1 = wmin1 + (float)(i1 + 2) * (wmax1 - wmin1) / 256.0f;
    const float thr2 = wmin2 + (float)(i2 + 2) * (wmax2 - wmin2) / 256.0f;

    code_s[t] = (b1 >= thr1 ? 1u : 0u) | (b2 >= thr2 ? 2u : 0u);
    __syncthreads();

    // ---- two sequential 1R:1W plane copies, branchless ----
    const unsigned int m = code_s[blockIdx.x & (NCH - 1)];
    const int base = (blockIdx.x << 12) | t;      // plane*4096 + t

    const f32x4* __restrict__ s1 = (m & 1u) ? x0 : x1;   // y1 source
    const f32x4* __restrict__ s2 = (m & 2u) ? x1 : x0;   // y2 source

#pragma unroll
    for (int u = 0; u < 16; ++u) {
        const int i = base + (u << 8);
        __builtin_nontemporal_store(__builtin_nontemporal_load(&s1[i]), &y1[i]);
    }
#pragma unroll
    for (int u = 0; u < 16; ++u) {
        const int i = base + (u << 8);
        __builtin_nontemporal_store(__builtin_nontemporal_load(&s2[i]), &y2[i]);
    }
}

extern "C" void kernel_launch(void* const* d_in, const int* in_sizes, int n_in,
                              void* d_out, int out_size, void* d_ws, size_t ws_size,
                              hipStream_t stream)
{
    const float* x0 = (const float*)d_in[0];
    const float* x1 = (const float*)d_in[1];
    const float* w1 = (const float*)d_in[2];
    const float* w2 = (const float*)d_in[3];

    const long long n4 = (long long)in_sizes[0] / 4;   // 8,388,608 = 2^23

    f32x4* y1 = (f32x4*)d_out;
    f32x4* y2 = y1 + n4;

    fused_kernel<<<2048, 256, 0, stream>>>(
        w1, w2, (const f32x4*)x0, (const f32x4*)x1, y1, y2);
}